// Round 2
// baseline (821.845 us; speedup 1.0000x reference)
//
#include <hip/hip_runtime.h>
#include <hip/hip_bf16.h>
#include <cstdint>
#include <cstddef>

typedef __attribute__((ext_vector_type(4))) float floatx4;
typedef __attribute__((ext_vector_type(8))) short shortx8;

typedef __attribute__((address_space(1))) void gvoid;
typedef __attribute__((address_space(3))) void lvoid;

__device__ inline __hip_bfloat16 f2b(float x) { return __float2bfloat16(x); }
__device__ inline float b2f(__hip_bfloat16 x) { return __bfloat162float(x); }
__device__ inline unsigned short f2bu(float x) {
  __hip_bfloat16 h = __float2bfloat16(x);
  return *reinterpret_cast<unsigned short*>(&h);
}

template <typename T> __device__ inline T cvt_out(float x);
template <> __device__ inline float cvt_out<float>(float x) { return x; }
template <> __device__ inline __hip_bfloat16 cvt_out<__hip_bfloat16>(float x) { return __float2bfloat16(x); }

// ---------------- elementwise f32 -> bf16 ----------------
__global__ void cvt_f32_bf16(const float* __restrict__ in, __hip_bfloat16* __restrict__ out, int n) {
  int i = (blockIdx.x * blockDim.x + threadIdx.x) * 4;
  if (i >= n) return;
  float4 v = *(const float4*)(in + i);
  __hip_bfloat16 o[4] = { f2b(v.x), f2b(v.y), f2b(v.z), f2b(v.w) };
  *(ushort4*)(out + i) = *(const ushort4*)o;
}

// ---------------- [K][N] f32 -> [N][K] bf16 (tiled transpose) ----------------
__global__ void transpose_cvt(const float* __restrict__ in, __hip_bfloat16* __restrict__ out, int K, int N) {
  __shared__ float tile[32][33];
  int n0 = blockIdx.x * 32, k0 = blockIdx.y * 32;
  int tx = threadIdx.x, ty = threadIdx.y;  // 32 x 8
#pragma unroll
  for (int i = 0; i < 4; i++)
    tile[ty + i * 8][tx] = in[(size_t)(k0 + ty + i * 8) * N + n0 + tx];
  __syncthreads();
#pragma unroll
  for (int i = 0; i < 4; i++)
    out[(size_t)(n0 + ty + i * 8) * K + k0 + tx] = f2b(tile[tx][ty + i * 8]);
}

// ---------------- bf16 GEMM: C[M][N] = A[M][K] * Bt[N][K]^T ----------------
template <typename OutT>
__global__ __launch_bounds__(256) void gemm_bt(
    const __hip_bfloat16* __restrict__ A,
    const __hip_bfloat16* __restrict__ Bt,
    OutT* __restrict__ C, int M, int N, int K) {
  __shared__ short lA[128 * 32];
  __shared__ short lB[128 * 32];
  const int m0 = blockIdx.x * 128, n0 = blockIdx.y * 128;
  const int t = threadIdx.x;
  const int l = t & 63;
  const int w = t >> 6;
  const int wm = (w & 1) * 64, wn = (w >> 1) * 64;
  const int lr = l & 15, lq = l >> 4;
  floatx4 acc[4][4] = {};

  for (int kt = 0; kt < K; kt += 32) {
    __syncthreads();
#pragma unroll
    for (int j = 0; j < 2; j++) {
      int flat = j * 2048 + t * 8;
      const __hip_bfloat16* srcA = A + (size_t)(m0 + (flat >> 5)) * K + kt + (flat & 31);
      __builtin_amdgcn_global_load_lds((gvoid*)srcA, (lvoid*)&lA[flat], 16, 0, 0);
      const __hip_bfloat16* srcB = Bt + (size_t)(n0 + (flat >> 5)) * K + kt + (flat & 31);
      __builtin_amdgcn_global_load_lds((gvoid*)srcB, (lvoid*)&lB[flat], 16, 0, 0);
    }
    __syncthreads();
    shortx8 af[4], bfr[4];
#pragma unroll
    for (int mi = 0; mi < 4; mi++)
      af[mi] = *(const shortx8*)&lA[(wm + mi * 16 + lr) * 32 + lq * 8];
#pragma unroll
    for (int ni = 0; ni < 4; ni++)
      bfr[ni] = *(const shortx8*)&lB[(wn + ni * 16 + lr) * 32 + lq * 8];
#pragma unroll
    for (int mi = 0; mi < 4; mi++)
#pragma unroll
      for (int ni = 0; ni < 4; ni++)
        acc[mi][ni] = __builtin_amdgcn_mfma_f32_16x16x32_bf16(af[mi], bfr[ni], acc[mi][ni], 0, 0, 0);
  }
#pragma unroll
  for (int mi = 0; mi < 4; mi++)
#pragma unroll
    for (int ni = 0; ni < 4; ni++) {
      int row = m0 + wm + mi * 16 + lq * 4;
      int col = n0 + wn + ni * 16 + lr;
#pragma unroll
      for (int r = 0; r < 4; r++)
        C[(size_t)(row + r) * N + col] = cvt_out<OutT>(acc[mi][ni][r]);
    }
}

// ---------------- in-place RoPE (+ optional score-scale fold) ----------------
__global__ void rope_kernel(__hip_bfloat16* __restrict__ q, int stride, float scale) {
  int i = threadIdx.x;                       // 0..31
  int row = blockIdx.x * 8 + threadIdx.y;    // 0..4095
  int head = blockIdx.y;
  int pos = row & 2047;
  float freq = (float)pos * exp2f(-(float)i * (13.287712379549449f / 32.0f));
  float s = sinf(freq), c = cosf(freq);
  __hip_bfloat16* p = q + (size_t)row * stride + head * 64 + i;
  float x1 = b2f(p[0]), x2 = b2f(p[32]);
  p[0]  = f2b((x1 * c - x2 * s) * scale);
  p[32] = f2b((x2 * c + x1 * s) * scale);
}

// ---------------- V slice of QKV -> Vt [B*NKV][64][2048] (LDS-tiled) ----------------
__global__ void v_transpose(const __hip_bfloat16* __restrict__ QKV, __hip_bfloat16* __restrict__ Vt) {
  __shared__ __hip_bfloat16 tile[32][33];
  int bkvh = blockIdx.z;                  // b*8+kvh
  int s0 = blockIdx.x * 32, d0 = blockIdx.y * 32;
  int b = bkvh >> 3, kvh = bkvh & 7;
  int tx = threadIdx.x, ty = threadIdx.y; // 32 x 8
#pragma unroll
  for (int i = 0; i < 4; i++)
    tile[ty + i * 8][tx] = QKV[(size_t)(b * 2048 + s0 + ty + i * 8) * 3072 + 2560 + kvh * 64 + d0 + tx];
  __syncthreads();
#pragma unroll
  for (int i = 0; i < 4; i++)
    Vt[((size_t)(bkvh * 64 + d0 + ty + i * 8) << 11) + s0 + tx] = tile[tx][ty + i * 8];
}

// ---------------- flash attention, barrier-free ----------------
// grid (32 qtiles, 32 heads, 2 batch); block 256 = 4 independent waves,
// each wave owns 16 q-rows. K/V/Q fragments loaded directly from global
// (L2-resident). S^T = K*Q^T so softmax reduction = in-reg tree + 2 shuffles.
// Q pre-scaled by 0.125*log2e so probs = exp2(s - m).
__global__ __launch_bounds__(256) void attn_kernel(
    const __hip_bfloat16* __restrict__ Q,   // QKV base, head slice h*64
    const __hip_bfloat16* __restrict__ K,   // QKV base + 2048
    const __hip_bfloat16* __restrict__ Vt,  // [B*8][64][2048]
    __hip_bfloat16* __restrict__ O) {       // [4096][2048]
  __shared__ __align__(16) short lP[4][16 * 64];  // per-wave P (A-layout, XOR-swizzled)
  const int qt = blockIdx.x, h = blockIdx.y, b = blockIdx.z;
  const int kvh = h >> 2;
  const int t = threadIdx.x, w = t >> 6, l = t & 63;
  const int lr = l & 15, lq = l >> 4;
  const int q0 = qt * 64 + w * 16;
  short* myP = &lP[w][0];

  // Q B-fragments (rows q0+lr, d = c*32 + lq*8 .. +7), held for the whole loop
  const __hip_bfloat16* qp = Q + (size_t)(b * 2048 + q0 + lr) * 3072 + h * 64 + lq * 8;
  shortx8 qf0 = *(const shortx8*)(qp);
  shortx8 qf1 = *(const shortx8*)(qp + 32);

  const __hip_bfloat16* kp = K + (size_t)(b * 2048 + lr) * 3072 + kvh * 64 + lq * 8;
  const __hip_bfloat16* vp = Vt + ((size_t)((b * 8 + kvh) * 64 + lr) << 11) + lq * 8;

  floatx4 oacc[4] = {};
  float m_run = -1e30f, l_run = 0.f;   // stats for column q = q0+lr (replicated over lq)

  for (int kt = 0; kt <= qt; kt++) {
    // K A-fragments: 4 m-tiles x 2 k-blocks (k-rows kt*64+mi*16+lr, d-cols)
    shortx8 kf[4][2], vf[4][2];
    const __hip_bfloat16* kb = kp + (size_t)(kt * 64) * 3072;
    const __hip_bfloat16* vb = vp + kt * 64;
#pragma unroll
    for (int mi = 0; mi < 4; mi++) {
      kf[mi][0] = *(const shortx8*)(kb + (size_t)(mi * 16) * 3072);
      kf[mi][1] = *(const shortx8*)(kb + (size_t)(mi * 16) * 3072 + 32);
    }
#pragma unroll
    for (int nj = 0; nj < 4; nj++) {
      vf[nj][0] = *(const shortx8*)(vb + (size_t)(nj * 16) * 2048);
      vf[nj][1] = *(const shortx8*)(vb + (size_t)(nj * 16) * 2048 + 32);
    }

    // S^T tiles: rows k (m), cols q (n).  C-layout: row k = lq*4+r, col q = lr.
    floatx4 sacc[4] = {};
#pragma unroll
    for (int mi = 0; mi < 4; mi++) {
      sacc[mi] = __builtin_amdgcn_mfma_f32_16x16x32_bf16(kf[mi][0], qf0, sacc[mi], 0, 0, 0);
      sacc[mi] = __builtin_amdgcn_mfma_f32_16x16x32_bf16(kf[mi][1], qf1, sacc[mi], 0, 0, 0);
    }

    if (kt == qt) {  // diagonal tile: mask k_abs > q_abs
#pragma unroll
      for (int mi = 0; mi < 4; mi++)
#pragma unroll
        for (int r = 0; r < 4; r++)
          if (mi * 16 + lq * 4 + r > w * 16 + lr) sacc[mi][r] = -3e8f;
    }

    // column (q) max: in-register tree + 2 shuffles across lq groups
    float mx = sacc[0][0];
#pragma unroll
    for (int mi = 0; mi < 4; mi++)
#pragma unroll
      for (int r = 0; r < 4; r++) mx = fmaxf(mx, sacc[mi][r]);
    mx = fmaxf(mx, __shfl_xor(mx, 16, 64));
    mx = fmaxf(mx, __shfl_xor(mx, 32, 64));
    float mnew = fmaxf(m_run, mx);
    float alpha = exp2f(m_run - mnew);
    m_run = mnew;

    float rs = 0.f;
#pragma unroll
    for (int mi = 0; mi < 4; mi++)
#pragma unroll
      for (int r = 0; r < 4; r++) {
        float pv = exp2f(sacc[mi][r] - mnew);
        sacc[mi][r] = pv;
        rs += pv;
      }
    rs += __shfl_xor(rs, 16, 64);
    rs += __shfl_xor(rs, 32, 64);
    l_run = l_run * alpha + rs;

    // P -> per-wave LDS as [q][k] A-layout, XOR-swizzled 16B chunks.
    // Lane holds col q=lr, k = mi*16+lq*4+r -> chunk (mi*2+(lq>>1))^(lr&7), half (lq&1)
#pragma unroll
    for (int mi = 0; mi < 4; mi++) {
      unsigned lo = (unsigned)f2bu(sacc[mi][0]) | ((unsigned)f2bu(sacc[mi][1]) << 16);
      unsigned hi = (unsigned)f2bu(sacc[mi][2]) | ((unsigned)f2bu(sacc[mi][3]) << 16);
      uint2 val; val.x = lo; val.y = hi;
      *(uint2*)(myP + lr * 64 + (((mi * 2 + (lq >> 1)) ^ (lr & 7)) << 3) + ((lq & 1) << 2)) = val;
    }
    // A-frag reads (same wave; HW orders via lgkmcnt)
    shortx8 pf0 = *(const shortx8*)(myP + lr * 64 + ((lq ^ (lr & 7)) << 3));
    shortx8 pf1 = *(const shortx8*)(myP + lr * 64 + (((4 + lq) ^ (lr & 7)) << 3));

    // redistribute alpha from column-space (q=lr) to row-space (q=lq*4+r)
    float a0 = __shfl(alpha, lq * 4 + 0, 64);
    float a1 = __shfl(alpha, lq * 4 + 1, 64);
    float a2 = __shfl(alpha, lq * 4 + 2, 64);
    float a3 = __shfl(alpha, lq * 4 + 3, 64);
#pragma unroll
    for (int nj = 0; nj < 4; nj++) {
      floatx4 o = oacc[nj];
      o[0] *= a0; o[1] *= a1; o[2] *= a2; o[3] *= a3;
      o = __builtin_amdgcn_mfma_f32_16x16x32_bf16(pf0, vf[nj][0], o, 0, 0, 0);
      o = __builtin_amdgcn_mfma_f32_16x16x32_bf16(pf1, vf[nj][1], o, 0, 0, 0);
      oacc[nj] = o;
    }
  }

  float linv = 1.0f / l_run;
  float l0 = __shfl(linv, lq * 4 + 0, 64);
  float l1 = __shfl(linv, lq * 4 + 1, 64);
  float l2 = __shfl(linv, lq * 4 + 2, 64);
  float l3 = __shfl(linv, lq * 4 + 3, 64);
  float lrow[4] = { l0, l1, l2, l3 };
  const size_t orow = (size_t)(b * 2048 + q0 + lq * 4);
#pragma unroll
  for (int nj = 0; nj < 4; nj++)
#pragma unroll
    for (int r = 0; r < 4; r++)
      O[(orow + r) * 2048 + h * 64 + nj * 16 + lr] = f2b(oacc[nj][r] * lrow[r]);
}

extern "C" void kernel_launch(void* const* d_in, const int* in_sizes, int n_in,
                              void* d_out, int out_size, void* d_ws, size_t ws_size,
                              hipStream_t stream) {
  (void)in_sizes; (void)n_in; (void)out_size; (void)ws_size;
  const float* hs = (const float*)d_in[0];
  const float* Wq = (const float*)d_in[3];
  const float* Wk = (const float*)d_in[4];
  const float* Wv = (const float*)d_in[5];
  const float* Wo = (const float*)d_in[6];
  float* out = (float*)d_out;

  char* p = (char*)d_ws;
  auto alloc = [&](size_t elts) { __hip_bfloat16* r = (__hip_bfloat16*)p; p += elts * 2; return r; };
  __hip_bfloat16* Xb   = alloc(4096ull * 4096);
  __hip_bfloat16* Wt   = alloc(3072ull * 4096);
  __hip_bfloat16* Wot  = alloc(2048ull * 2048);
  __hip_bfloat16* QKVb = alloc(4096ull * 3072);
  __hip_bfloat16* Vtb  = alloc(2ull * 8 * 64 * 2048);
  __hip_bfloat16* Ab   = alloc(4096ull * 2048);

  cvt_f32_bf16<<<16384, 256, 0, stream>>>(hs, Xb, 4096 * 4096);
  transpose_cvt<<<dim3(64, 128), dim3(32, 8), 0, stream>>>(Wq, Wt, 4096, 2048);
  transpose_cvt<<<dim3(16, 128), dim3(32, 8), 0, stream>>>(Wk, Wt + 2048ull * 4096, 4096, 512);
  transpose_cvt<<<dim3(16, 128), dim3(32, 8), 0, stream>>>(Wv, Wt + 2560ull * 4096, 4096, 512);
  transpose_cvt<<<dim3(64, 64), dim3(32, 8), 0, stream>>>(Wo, Wot, 2048, 2048);

  gemm_bt<__hip_bfloat16><<<dim3(32, 24), 256, 0, stream>>>(Xb, Wt, QKVb, 4096, 3072, 4096);

  // Q pre-scaled by 1/sqrt(64) * log2(e) so attention softmax uses exp2 directly
  rope_kernel<<<dim3(512, 32), dim3(32, 8), 0, stream>>>(QKVb, 3072, 0.18033688011112042f);
  rope_kernel<<<dim3(512, 8), dim3(32, 8), 0, stream>>>(QKVb + 2048, 3072, 1.0f);
  v_transpose<<<dim3(64, 2, 16), dim3(32, 8), 0, stream>>>(QKVb, Vtb);

  attn_kernel<<<dim3(32, 32, 2), 256, 0, stream>>>(QKVb, QKVb + 2048, Vtb, Ab);

  gemm_bt<float><<<dim3(32, 16), 256, 0, stream>>>(Ab, Wot, out, 4096, 2048, 2048);
}

// Round 3
// 578.843 us; speedup vs baseline: 1.4198x; 1.4198x over previous
//
#include <hip/hip_runtime.h>
#include <hip/hip_bf16.h>
#include <cstdint>
#include <cstddef>

typedef __attribute__((ext_vector_type(4))) float floatx4;
typedef __attribute__((ext_vector_type(8))) short shortx8;

typedef __attribute__((address_space(1))) void gvoid;
typedef __attribute__((address_space(3))) void lvoid;

__device__ inline __hip_bfloat16 f2b(float x) { return __float2bfloat16(x); }
__device__ inline float b2f(__hip_bfloat16 x) { return __bfloat162float(x); }
__device__ inline unsigned short f2bu(float x) {
  __hip_bfloat16 h = __float2bfloat16(x);
  return *reinterpret_cast<unsigned short*>(&h);
}

template <typename T> __device__ inline T cvt_out(float x);
template <> __device__ inline float cvt_out<float>(float x) { return x; }
template <> __device__ inline __hip_bfloat16 cvt_out<__hip_bfloat16>(float x) { return __float2bfloat16(x); }

// ---------------- elementwise f32 -> bf16 ----------------
__global__ void cvt_f32_bf16(const float* __restrict__ in, __hip_bfloat16* __restrict__ out, int n) {
  int i = (blockIdx.x * blockDim.x + threadIdx.x) * 4;
  if (i >= n) return;
  float4 v = *(const float4*)(in + i);
  __hip_bfloat16 o[4] = { f2b(v.x), f2b(v.y), f2b(v.z), f2b(v.w) };
  *(ushort4*)(out + i) = *(const ushort4*)o;
}

// ---------------- [K][N] f32 -> [N][K] bf16 (tiled transpose) ----------------
__global__ void transpose_cvt(const float* __restrict__ in, __hip_bfloat16* __restrict__ out, int K, int N) {
  __shared__ float tile[32][33];
  int n0 = blockIdx.x * 32, k0 = blockIdx.y * 32;
  int tx = threadIdx.x, ty = threadIdx.y;  // 32 x 8
#pragma unroll
  for (int i = 0; i < 4; i++)
    tile[ty + i * 8][tx] = in[(size_t)(k0 + ty + i * 8) * N + n0 + tx];
  __syncthreads();
#pragma unroll
  for (int i = 0; i < 4; i++)
    out[(size_t)(n0 + ty + i * 8) * K + k0 + tx] = f2b(tile[tx][ty + i * 8]);
}

// ---------------- bf16 GEMM: C[M][N] = A[M][K] * Bt[N][K]^T (m97 structure) ----------------
template <typename OutT>
__global__ __launch_bounds__(256) void gemm_bt(
    const __hip_bfloat16* __restrict__ A,
    const __hip_bfloat16* __restrict__ Bt,
    OutT* __restrict__ C, int M, int N, int K) {
  __shared__ short lA[128 * 32];
  __shared__ short lB[128 * 32];
  const int m0 = blockIdx.x * 128, n0 = blockIdx.y * 128;
  const int t = threadIdx.x;
  const int l = t & 63;
  const int w = t >> 6;
  const int wm = (w & 1) * 64, wn = (w >> 1) * 64;
  const int lr = l & 15, lq = l >> 4;
  floatx4 acc[4][4] = {};

  for (int kt = 0; kt < K; kt += 32) {
    __syncthreads();
#pragma unroll
    for (int j = 0; j < 2; j++) {
      int flat = j * 2048 + t * 8;
      const __hip_bfloat16* srcA = A + (size_t)(m0 + (flat >> 5)) * K + kt + (flat & 31);
      __builtin_amdgcn_global_load_lds((gvoid*)srcA, (lvoid*)&lA[flat], 16, 0, 0);
      const __hip_bfloat16* srcB = Bt + (size_t)(n0 + (flat >> 5)) * K + kt + (flat & 31);
      __builtin_amdgcn_global_load_lds((gvoid*)srcB, (lvoid*)&lB[flat], 16, 0, 0);
    }
    __syncthreads();
    shortx8 af[4], bfr[4];
#pragma unroll
    for (int mi = 0; mi < 4; mi++)
      af[mi] = *(const shortx8*)&lA[(wm + mi * 16 + lr) * 32 + lq * 8];
#pragma unroll
    for (int ni = 0; ni < 4; ni++)
      bfr[ni] = *(const shortx8*)&lB[(wn + ni * 16 + lr) * 32 + lq * 8];
#pragma unroll
    for (int mi = 0; mi < 4; mi++)
#pragma unroll
      for (int ni = 0; ni < 4; ni++)
        acc[mi][ni] = __builtin_amdgcn_mfma_f32_16x16x32_bf16(af[mi], bfr[ni], acc[mi][ni], 0, 0, 0);
  }
#pragma unroll
  for (int mi = 0; mi < 4; mi++)
#pragma unroll
    for (int ni = 0; ni < 4; ni++) {
      int row = m0 + wm + mi * 16 + lq * 4;
      int col = n0 + wn + ni * 16 + lr;
#pragma unroll
      for (int r = 0; r < 4; r++)
        C[(size_t)(row + r) * N + col] = cvt_out<OutT>(acc[mi][ni][r]);
    }
}

// ---------------- in-place RoPE (+ optional score-scale fold) ----------------
__global__ void rope_kernel(__hip_bfloat16* __restrict__ q, int stride, float scale) {
  int i = threadIdx.x;                       // 0..31
  int row = blockIdx.x * 8 + threadIdx.y;    // 0..4095
  int head = blockIdx.y;
  int pos = row & 2047;
  float freq = (float)pos * exp2f(-(float)i * (13.287712379549449f / 32.0f));
  float s = sinf(freq), c = cosf(freq);
  __hip_bfloat16* p = q + (size_t)row * stride + head * 64 + i;
  float x1 = b2f(p[0]), x2 = b2f(p[32]);
  p[0]  = f2b((x1 * c - x2 * s) * scale);
  p[32] = f2b((x2 * c + x1 * s) * scale);
}

// ---------------- V slice of QKV -> Vt [B*NKV][64][2048] (LDS-tiled) ----------------
__global__ void v_transpose(const __hip_bfloat16* __restrict__ QKV, __hip_bfloat16* __restrict__ Vt) {
  __shared__ __hip_bfloat16 tile[32][33];
  int bkvh = blockIdx.z;                  // b*8+kvh
  int s0 = blockIdx.x * 32, d0 = blockIdx.y * 32;
  int b = bkvh >> 3, kvh = bkvh & 7;
  int tx = threadIdx.x, ty = threadIdx.y; // 32 x 8
#pragma unroll
  for (int i = 0; i < 4; i++)
    tile[ty + i * 8][tx] = QKV[(size_t)(b * 2048 + s0 + ty + i * 8) * 3072 + 2560 + kvh * 64 + d0 + tx];
  __syncthreads();
#pragma unroll
  for (int i = 0; i < 4; i++)
    Vt[((size_t)(bkvh * 64 + d0 + ty + i * 8) << 11) + s0 + tx] = tile[tx][ty + i * 8];
}

// ---------------- flash attention: dbuf LDS, 1 barrier/iter, swizzled ----------------
// grid (16 qtiles reversed, 32 h, 2 b); block 256 = 4 waves.
// Block owns 128 q rows; wave w owns 16-row tiles A (w*16) and B (64+w*16).
// K/V staged via VGPR->LDS with XOR swizzle (chunk ^= row&7): frag reads 2-way = free.
// S^T = K*Q^T (stats in q=lane&15 space); O^T = V^T*P keeps q in same space ->
// alpha rescale and 1/l are per-lane scalars, no shuffles.
// Q pre-scaled by 0.125*log2e so probs = exp2(s - m).
__global__ __launch_bounds__(256, 3) void attn_kernel(
    const __hip_bfloat16* __restrict__ Qp,  // QKV base (q at h*64)
    const __hip_bfloat16* __restrict__ Kp,  // QKV base + 2048
    const __hip_bfloat16* __restrict__ Vt,  // [B*8][64][2048]
    __hip_bfloat16* __restrict__ O) {       // [4096][2048]
  __shared__ __align__(16) short lK[2][64 * 64];
  __shared__ __align__(16) short lV[2][64 * 64];
  __shared__ __align__(16) short lP[4][16 * 64];
  const int qt = (int)gridDim.x - 1 - (int)blockIdx.x;  // heavy blocks first
  const int h = blockIdx.y, b = blockIdx.z;
  const int kvh = h >> 2;
  const int t = threadIdx.x, w = t >> 6, l = t & 63;
  const int lr = l & 15, lq = l >> 4;
  const int swz = lr & 7;

  const int q0A = qt * 128 + w * 16;
  // Q B-frags (n=q=lr, k=d=lq*8+j), once for the whole loop
  const __hip_bfloat16* qpA = Qp + (size_t)(b * 2048 + q0A + lr) * 3072 + h * 64 + lq * 8;
  shortx8 qfA0 = *(const shortx8*)(qpA);
  shortx8 qfA1 = *(const shortx8*)(qpA + 32);
  shortx8 qfB0 = *(const shortx8*)(qpA + 64 * 3072);
  shortx8 qfB1 = *(const shortx8*)(qpA + 64 * 3072 + 32);

  // staging: thread stages 2x16B of K and V per tile; row = t>>3 (+j*32), chunk = t&7
  const int srow = t >> 3, schunk = t & 7;
  const __hip_bfloat16* ksrc = Kp + (size_t)(b * 2048 + srow) * 3072 + kvh * 64 + schunk * 8;
  const __hip_bfloat16* vsrc = Vt + ((size_t)((b * 8 + kvh) * 64 + srow) << 11) + schunk * 8;
  const int ldst = srow * 64 + ((schunk ^ (srow & 7)) << 3);
  short* const myP = &lP[w][0];

  floatx4 oA[4] = {}, oB[4] = {};
  float mA = -1e30f, sumA = 0.f, mB = -1e30f, sumB = 0.f;

  uint4 kreg[2], vreg[2];
  const int KT = 2 * qt + 2;
#pragma unroll
  for (int j = 0; j < 2; j++) {
    kreg[j] = *(const uint4*)(ksrc + (size_t)(j * 32) * 3072);
    vreg[j] = *(const uint4*)(vsrc + (size_t)(j * 32) * 2048);
  }

  for (int kt = 0; kt < KT; kt++) {
    const int buf = kt & 1;
#pragma unroll
    for (int j = 0; j < 2; j++) {
      *(uint4*)&lK[buf][ldst + j * 2048] = kreg[j];
      *(uint4*)&lV[buf][ldst + j * 2048] = vreg[j];
    }
    __syncthreads();
    if (kt + 1 < KT) {
#pragma unroll
      for (int j = 0; j < 2; j++) {
        kreg[j] = *(const uint4*)(ksrc + (size_t)((kt + 1) * 64 + j * 32) * 3072);
        vreg[j] = *(const uint4*)(vsrc + (size_t)(j * 32) * 2048 + (kt + 1) * 64);
      }
    }
    const bool doA = (kt <= 2 * qt);   // tile A fully masked on the last k-tile

    // S^T = K * Q^T  (kf shared across both q-tiles)
    floatx4 sA[4] = {}, sB[4] = {};
#pragma unroll
    for (int mi = 0; mi < 4; mi++) {
      const short* kr = &lK[buf][(mi * 16 + lr) * 64];
      shortx8 kf0 = *(const shortx8*)(kr + ((lq ^ swz) << 3));
      shortx8 kf1 = *(const shortx8*)(kr + (((4 + lq) ^ swz) << 3));
      if (doA) {
        sA[mi] = __builtin_amdgcn_mfma_f32_16x16x32_bf16(kf0, qfA0, sA[mi], 0, 0, 0);
        sA[mi] = __builtin_amdgcn_mfma_f32_16x16x32_bf16(kf1, qfA1, sA[mi], 0, 0, 0);
      }
      sB[mi] = __builtin_amdgcn_mfma_f32_16x16x32_bf16(kf0, qfB0, sB[mi], 0, 0, 0);
      sB[mi] = __builtin_amdgcn_mfma_f32_16x16x32_bf16(kf1, qfB1, sB[mi], 0, 0, 0);
    }

    shortx8 pA0, pA1, pB0, pB1;
    float alphaA = 1.f, alphaB = 1.f;

    if (doA) {
      if (kt == 2 * qt) {  // diagonal tile: mask k_rel > w*16 + lr
#pragma unroll
        for (int mi = 0; mi < 4; mi++)
#pragma unroll
          for (int r = 0; r < 4; r++)
            if (mi * 16 + lq * 4 + r > w * 16 + lr) sA[mi][r] = -3e8f;
      }
      float mx = sA[0][0];
#pragma unroll
      for (int mi = 0; mi < 4; mi++)
#pragma unroll
        for (int r = 0; r < 4; r++) mx = fmaxf(mx, sA[mi][r]);
      mx = fmaxf(mx, __shfl_xor(mx, 16, 64));
      mx = fmaxf(mx, __shfl_xor(mx, 32, 64));
      float mnew = fmaxf(mA, mx);
      alphaA = exp2f(mA - mnew);
      mA = mnew;
      float rs = 0.f;
#pragma unroll
      for (int mi = 0; mi < 4; mi++)
#pragma unroll
        for (int r = 0; r < 4; r++) {
          float pv = exp2f(sA[mi][r] - mnew);
          sA[mi][r] = pv;
          rs += pv;
        }
      rs += __shfl_xor(rs, 16, 64);
      rs += __shfl_xor(rs, 32, 64);
      sumA = sumA * alphaA + rs;
      // bounce P_A (C-layout) -> A-layout [q=lr][k], swizzled; same-wave ordering via DS FIFO
#pragma unroll
      for (int mi = 0; mi < 4; mi++) {
        uint2 val;
        val.x = (unsigned)f2bu(sA[mi][0]) | ((unsigned)f2bu(sA[mi][1]) << 16);
        val.y = (unsigned)f2bu(sA[mi][2]) | ((unsigned)f2bu(sA[mi][3]) << 16);
        *(uint2*)(myP + lr * 64 + (((mi * 2 + (lq >> 1)) ^ swz) << 3) + ((lq & 1) << 2)) = val;
      }
      pA0 = *(const shortx8*)(myP + lr * 64 + ((lq ^ swz) << 3));
      pA1 = *(const shortx8*)(myP + lr * 64 + (((4 + lq) ^ swz) << 3));
    }

    {
      if (kt == 2 * qt + 1) {  // tile B diagonal on the last k-tile
#pragma unroll
        for (int mi = 0; mi < 4; mi++)
#pragma unroll
          for (int r = 0; r < 4; r++)
            if (mi * 16 + lq * 4 + r > w * 16 + lr) sB[mi][r] = -3e8f;
      }
      float mx = sB[0][0];
#pragma unroll
      for (int mi = 0; mi < 4; mi++)
#pragma unroll
        for (int r = 0; r < 4; r++) mx = fmaxf(mx, sB[mi][r]);
      mx = fmaxf(mx, __shfl_xor(mx, 16, 64));
      mx = fmaxf(mx, __shfl_xor(mx, 32, 64));
      float mnew = fmaxf(mB, mx);
      alphaB = exp2f(mB - mnew);
      mB = mnew;
      float rs = 0.f;
#pragma unroll
      for (int mi = 0; mi < 4; mi++)
#pragma unroll
        for (int r = 0; r < 4; r++) {
          float pv = exp2f(sB[mi][r] - mnew);
          sB[mi][r] = pv;
          rs += pv;
        }
      rs += __shfl_xor(rs, 16, 64);
      rs += __shfl_xor(rs, 32, 64);
      sumB = sumB * alphaB + rs;
#pragma unroll
      for (int mi = 0; mi < 4; mi++) {
        uint2 val;
        val.x = (unsigned)f2bu(sB[mi][0]) | ((unsigned)f2bu(sB[mi][1]) << 16);
        val.y = (unsigned)f2bu(sB[mi][2]) | ((unsigned)f2bu(sB[mi][3]) << 16);
        *(uint2*)(myP + lr * 64 + (((mi * 2 + (lq >> 1)) ^ swz) << 3) + ((lq & 1) << 2)) = val;
      }
      pB0 = *(const shortx8*)(myP + lr * 64 + ((lq ^ swz) << 3));
      pB1 = *(const shortx8*)(myP + lr * 64 + (((4 + lq) ^ swz) << 3));
    }

    // O^T += V^T * P   (vf shared across both q-tiles; alpha is per-lane scalar)
#pragma unroll
    for (int mi = 0; mi < 4; mi++) {
      const short* vr = &lV[buf][(mi * 16 + lr) * 64];
      shortx8 vf0 = *(const shortx8*)(vr + ((lq ^ swz) << 3));
      shortx8 vf1 = *(const shortx8*)(vr + (((4 + lq) ^ swz) << 3));
      if (doA) {
        floatx4 o = oA[mi];
#pragma unroll
        for (int r = 0; r < 4; r++) o[r] *= alphaA;
        o = __builtin_amdgcn_mfma_f32_16x16x32_bf16(vf0, pA0, o, 0, 0, 0);
        o = __builtin_amdgcn_mfma_f32_16x16x32_bf16(vf1, pA1, o, 0, 0, 0);
        oA[mi] = o;
      }
      floatx4 o2 = oB[mi];
#pragma unroll
      for (int r = 0; r < 4; r++) o2[r] *= alphaB;
      o2 = __builtin_amdgcn_mfma_f32_16x16x32_bf16(vf0, pB0, o2, 0, 0, 0);
      o2 = __builtin_amdgcn_mfma_f32_16x16x32_bf16(vf1, pB1, o2, 0, 0, 0);
      oB[mi] = o2;
    }
  }

  // epilogue: O^T lane holds (d = mi*16+lq*4+r, q = q0+lr); 8B packed stores
  const float livA = 1.f / sumA, livB = 1.f / sumB;
  __hip_bfloat16* obase = O + (size_t)(b * 2048 + q0A + lr) * 2048 + h * 64 + lq * 4;
#pragma unroll
  for (int mi = 0; mi < 4; mi++) {
    ushort4 pk;
    pk.x = f2bu(oA[mi][0] * livA); pk.y = f2bu(oA[mi][1] * livA);
    pk.z = f2bu(oA[mi][2] * livA); pk.w = f2bu(oA[mi][3] * livA);
    *(ushort4*)(obase + mi * 16) = pk;
  }
  __hip_bfloat16* obase2 = obase + (size_t)64 * 2048;
#pragma unroll
  for (int mi = 0; mi < 4; mi++) {
    ushort4 pk;
    pk.x = f2bu(oB[mi][0] * livB); pk.y = f2bu(oB[mi][1] * livB);
    pk.z = f2bu(oB[mi][2] * livB); pk.w = f2bu(oB[mi][3] * livB);
    *(ushort4*)(obase2 + mi * 16) = pk;
  }
}

extern "C" void kernel_launch(void* const* d_in, const int* in_sizes, int n_in,
                              void* d_out, int out_size, void* d_ws, size_t ws_size,
                              hipStream_t stream) {
  (void)in_sizes; (void)n_in; (void)out_size; (void)ws_size;
  const float* hs = (const float*)d_in[0];
  const float* Wq = (const float*)d_in[3];
  const float* Wk = (const float*)d_in[4];
  const float* Wv = (const float*)d_in[5];
  const float* Wo = (const float*)d_in[6];
  float* out = (float*)d_out;

  char* p = (char*)d_ws;
  auto alloc = [&](size_t elts) { __hip_bfloat16* r = (__hip_bfloat16*)p; p += elts * 2; return r; };
  __hip_bfloat16* Xb   = alloc(4096ull * 4096);
  __hip_bfloat16* Wt   = alloc(3072ull * 4096);
  __hip_bfloat16* Wot  = alloc(2048ull * 2048);
  __hip_bfloat16* QKVb = alloc(4096ull * 3072);
  __hip_bfloat16* Vtb  = alloc(2ull * 8 * 64 * 2048);
  __hip_bfloat16* Ab   = alloc(4096ull * 2048);

  cvt_f32_bf16<<<16384, 256, 0, stream>>>(hs, Xb, 4096 * 4096);
  transpose_cvt<<<dim3(64, 128), dim3(32, 8), 0, stream>>>(Wq, Wt, 4096, 2048);
  transpose_cvt<<<dim3(16, 128), dim3(32, 8), 0, stream>>>(Wk, Wt + 2048ull * 4096, 4096, 512);
  transpose_cvt<<<dim3(16, 128), dim3(32, 8), 0, stream>>>(Wv, Wt + 2560ull * 4096, 4096, 512);
  transpose_cvt<<<dim3(64, 64), dim3(32, 8), 0, stream>>>(Wo, Wot, 2048, 2048);

  gemm_bt<__hip_bfloat16><<<dim3(32, 24), 256, 0, stream>>>(Xb, Wt, QKVb, 4096, 3072, 4096);

  // Q pre-scaled by 1/sqrt(64) * log2(e) so attention softmax uses exp2 directly
  rope_kernel<<<dim3(512, 32), dim3(32, 8), 0, stream>>>(QKVb, 3072, 0.18033688011112042f);
  rope_kernel<<<dim3(512, 8), dim3(32, 8), 0, stream>>>(QKVb + 2048, 3072, 1.0f);
  v_transpose<<<dim3(64, 2, 16), dim3(32, 8), 0, stream>>>(QKVb, Vtb);

  attn_kernel<<<dim3(16, 32, 2), 256, 0, stream>>>(QKVb, QKVb + 2048, Vtb, Ab);

  gemm_bt<float><<<dim3(32, 16), 256, 0, stream>>>(Ab, Wot, out, 4096, 2048, 2048);
}